// Round 14
// baseline (249.276 us; speedup 1.0000x reference)
//
#include <hip/hip_runtime.h>
#include <hip/hip_bf16.h>

#define NNODES 50000
#define NEDGES 1600000
#define DD 128
#define EPSF 1e-6f
#define NB_SCAN 196   // ceil(50000/256)
#define NPART 32      // edge partitions (cbase u16 -> 3.2MB, per-XCD-L2-fit)
#define EPP 50000     // edges per partition (NPART*EPP = NEDGES)
#define NRG 8         // rowgroups (25KB LDS per hist block -> 6 blocks/CU)
#define RGSZ 6250     // rows per rowgroup (NRG*RGSZ = NNODES)

using u32 = unsigned int;
using u16 = unsigned short;
using u64 = unsigned long long;
typedef __attribute__((ext_vector_type(8))) short v8s;   // 8 x bf16 (4 VGPR)
typedef __attribute__((ext_vector_type(4))) float v4f;   // mfma accumulator
typedef __attribute__((ext_vector_type(4))) int   v4i;   // i8 mfma operand (16 i8)
typedef __attribute__((ext_vector_type(2))) float v2f;   // nontemporal-storable pair

static __device__ __forceinline__ float b2f16(u16 v) { return __uint_as_float(((u32)v) << 16); }
static __device__ __forceinline__ u16 f2b(float f) {
    u32 u = __float_as_uint(f);
    return (u16)((u + 0x7fffu + ((u >> 16) & 1u)) >> 16);
}
static __device__ __forceinline__ float tanh_pos(float a) {   // a >= 0, fast
    float e = __expf(-2.f * a);
    return __fdividef(1.f - e, 1.f + e);
}

// workspace byte offsets — ALL gather pools 128B-aligned
#define OFF_GFRAG  0          // 3 * 32KB bf16 Gram matrices in MFMA B-frag layout
#define OFF_PHICHI 98304      // 50000 f32
#define OFF_VSX    298304     // 50000 float2 : (vsq, xscale) per node
#define OFF_CNT    698304     // 50000 u32 row totals (cursor alias in fallback)
#define OFF_START  898304     // 50001 u32 (pad to 200064)
#define OFF_BSUM   1098368    // 196 u32 (pad 1024)
#define OFF_ABSC   1100416    // 50000 float2 : (ascale, bscale)
#define OFF_AQ     1500416    // 50000*128 i8 (128-aligned)
#define OFF_BQ     7900416    // 50000*128 i8 (128-aligned)
#define OFF_XB     14300416   // 50000*128 bf16 (128-aligned)
#define OFF_XQ     27100416   // 50000*128 i8 gather pool (128-aligned)
#define OFF_EREC   33500416   // 1.6M u32 : (col<<15)|bf16w (64-aligned)
#define OFF_WCOMB  33500416   // 128*128 f32 TEMP, overlays EREC (dead before k_mid)
#define OFF_RANK   39900416   // 1.6M u16 : rank within (partition,row)
#define OFF_CBASE  43100416   // 32*50000 u16 : per-(part,row) counts -> excl bases (3.2MB)
#define WS_NEED_RANK 46300416ull

// store val=G[a][c] into MFMA B-fragment layout for mfma_f32_16x16x32_bf16
static __device__ __forceinline__ void gstore(u16* gf, int mat, int a, int c, float v) {
    int lane = (((a >> 3) & 3) << 4) | (c & 15);
    int u = ((((mat*8 + (c >> 4))*4 + (a >> 5))*64 + lane) << 3) | (a & 7);
    gf[u] = f2b(v);
}

#define HB (NEDGES/256)       // 6250 fallback hist blocks
#define XBLK (NNODES/4)       // 12500 x-quant blocks (1 node/wave)

// SEPARATE k_hist (R14: R13's fusion taxed all k_prep roles with 50KB LDS —
// reverted). 32 partitions x 8 rowgroups = 256 blocks, 25KB LDS each.
__global__ __launch_bounds__(256) void k_hist(const int* __restrict__ ei,
                                              u16* __restrict__ rank,
                                              u16* __restrict__ cbase) {
    __shared__ u32 lcnt[RGSZ];
    int p = blockIdx.x >> 3, rg = blockIdx.x & 7;
    int t = threadIdx.x;
    for (int i = t; i < RGSZ; i += 256) lcnt[i] = 0;
    __syncthreads();
    int base = rg * RGSZ;
    for (int i = t; i < EPP; i += 256) {
        int e = p*EPP + i;
        int r = ei[e];
        u32 rr = (u32)(r - base);
        if (rr < RGSZ) {
            u32 old = atomicAdd(&lcnt[rr], 1u);   // LDS atomic, returns order
            rank[e] = (u16)old;
        }
    }
    __syncthreads();
    u16* dst = cbase + (size_t)p*NNODES + base;
    for (int i = t; i < RGSZ; i += 256) dst[i] = (u16)lcnt[i];
}

// RANK path: quant (XBLK blocks) + weight GEMMs (192 blocks). No LDS.
// Fallback: + HB device-atomic histogram blocks in front.
template<bool RANK>
__global__ __launch_bounds__(256) void k_prep(const int* __restrict__ ei,
                                              const float* __restrict__ x,
                                              const float* __restrict__ Wchi,
                                              const float* __restrict__ Wphi,
                                              const float* __restrict__ Wvphi,
                                              u32* __restrict__ cnt,
                                              u16* __restrict__ xb,
                                              char* __restrict__ xq,
                                              float* __restrict__ vsx,
                                              float* __restrict__ wcomb,
                                              u16* __restrict__ gf) {
    int b = blockIdx.x, t = threadIdx.x;
    if (!RANK) {
        if (b < HB) {                              // fallback: device-atomic histogram
            atomicAdd(&cnt[ei[b*256 + t]], 1u);
            return;
        }
        b -= HB;
    }
    if (b < XBLK) {
        // x -> bf16 xb + i8 xq (per-node absmax scale). 1 node per wave.
        int w = t >> 6, lane = t & 63;
        int node = b*4 + w;
        float2 xv = ((const float2*)(x + (size_t)node*DD))[lane];
        u32 pk = (u32)f2b(xv.x) | ((u32)f2b(xv.y) << 16);
        ((u32*)xb)[node*64 + lane] = pk;
        float m = fmaxf(fabsf(xv.x), fabsf(xv.y));
        #pragma unroll
        for (int mask = 1; mask < 64; mask <<= 1)
            m = fmaxf(m, __shfl_xor(m, mask));
        float inv = (m > 0.f) ? 127.f/m : 0.f;
        int q0 = (int)rintf(xv.x*inv), q1 = (int)rintf(xv.y*inv);
        ((u16*)xq)[node*64 + lane] = (u16)((q0 & 0xff) | ((q1 & 0xff) << 8));
        if (lane == 0) vsx[2*node + 1] = m * (1.f/127.f);
        return;
    }
    // weight role: bb<64 -> Wcomb = Wphi@Wchi (fp32 temp);
    //              bb<128 -> Bgram -> frag mat 1;  else Cgram -> frag mat 2
    int bb = b - XBLK;
    if (bb < 64) {
        int idx = bb*256 + t;
        int i = idx >> 7, k = idx & 127;
        float acc = 0.f;
        #pragma unroll 8
        for (int m = 0; m < DD; ++m)
            acc = fmaf(Wphi[i*DD+m], Wchi[m*DD+k], acc);
        wcomb[i*DD+k] = acc;
    } else {
        const float* W = (bb < 128) ? Wvphi : Wchi;
        int mat = (bb < 128) ? 1 : 2;
        int idx = ((bb & 63))*256 + t;
        int a = idx >> 7, c = idx & 127;
        float acc = 0.f;
        #pragma unroll 8
        for (int m = 0; m < DD; ++m)
            acc = fmaf(W[m*DD+a], W[m*DD+c], acc);
        gstore(gf, mat, a, c, acc);
    }
}

// FUSED: rowsum (cbase counts -> exclusive prefixes + cnt) + per-block degree
// sums, block-local dependency only. Blocks >= NB_SCAN compute Agram -> frag mat 0.
template<bool RANK>
__global__ __launch_bounds__(256) void k_rowsum_bsum(u16* __restrict__ cbase,
                                                     u32* __restrict__ cnt,
                                                     u32* __restrict__ bsum,
                                                     const float* __restrict__ wcomb,
                                                     u16* __restrict__ gf) {
    if (blockIdx.x >= NB_SCAN) {
        int idx = (blockIdx.x - NB_SCAN)*256 + threadIdx.x;
        int a = idx >> 7, c = idx & 127;
        float acc = 0.f;
        #pragma unroll 8
        for (int m = 0; m < DD; ++m)
            acc = fmaf(wcomb[m*DD+a], wcomb[m*DD+c], acc);
        gstore(gf, 0, a, c, acc);
        return;
    }
    __shared__ u32 s[256];
    int r = blockIdx.x*256 + threadIdx.x;
    u32 running = 0;
    if (RANK) {
        if (r < NNODES) {
            #pragma unroll
            for (int p = 0; p < NPART; ++p) {
                u32 c = cbase[(size_t)p*NNODES + r];
                cbase[(size_t)p*NNODES + r] = (u16)running;
                running += c;
            }
            cnt[r] = running;
        }
    } else {
        running = (r < NNODES) ? cnt[r] : 0u;
    }
    s[threadIdx.x] = (r < NNODES) ? running : 0u;
    __syncthreads();
    for (int off = 128; off > 0; off >>= 1) {
        if (threadIdx.x < off) s[threadIdx.x] += s[threadIdx.x + off];
        __syncthreads();
    }
    if (threadIdx.x == 0) bsum[blockIdx.x] = s[0];
}

// FUSED: block-exclusive boff computed inline (sum of bsum[0..bid)), then
// the per-block scan of cnt. One fewer launch.
__global__ __launch_bounds__(256) void k_scan_final(const u32* __restrict__ cnt,
                                                    const u32* __restrict__ bsum,
                                                    u32* __restrict__ start,
                                                    u32* __restrict__ cursor) {
    __shared__ u32 s[256];
    __shared__ u32 sb[256];
    int t = threadIdx.x;
    u32 pre = 0;
    for (int j = t; j < (int)blockIdx.x; j += 256) pre += bsum[j];
    sb[t] = pre;
    __syncthreads();
    for (int off = 128; off > 0; off >>= 1) {
        if (t < off) sb[t] += sb[t + off];
        __syncthreads();
    }
    u32 boff = sb[0];
    int i = blockIdx.x*256 + t;
    u32 v = (i < NNODES) ? cnt[i] : 0u;
    s[t] = v;
    __syncthreads();
    for (int off = 1; off < 256; off <<= 1) {
        u32 a = (t >= off) ? s[t - off] : 0u;
        __syncthreads();
        s[t] += a;
        __syncthreads();
    }
    if (i < NNODES) {
        u32 val = boff + (s[t] - v);
        start[i]  = val;
        cursor[i] = val;
        if (i == NNODES-1) start[NNODES] = val + v;
    }
}

#define SB (NEDGES/256)       // 6250 scatter blocks
#define GB 782                // gemm blocks: 64 nodes each
// grid = SB + GB = 7032; b%9==0 -> gemm (782 exactly), else scatter

template<bool RANK>
__global__ __launch_bounds__(256) void k_mid(const int* __restrict__ ei,
                                             const float* __restrict__ ew,
                                             const u32* __restrict__ start,
                                             u32* __restrict__ cursor,
                                             const u16* __restrict__ rank,
                                             const u16* __restrict__ cbase,
                                             u32* __restrict__ erec,
                                             const u16* __restrict__ xb,
                                             float* __restrict__ ws,
                                             char* __restrict__ aq,
                                             char* __restrict__ bq,
                                             float* __restrict__ absc) {
    int b = blockIdx.x, t = threadIdx.x;
    if (b % 9 != 0) {                              // scatter into CSR (4B packed record)
        int eb = b - b/9 - 1;
        int e = eb*256 + t;
        int r = __builtin_nontemporal_load(&ei[e]);
        u32 pos;
        if (RANK) {
            int p = e / EPP;                       // partition, same map as k_hist
            pos = start[r] + (u32)cbase[(size_t)p*NNODES + r]
                + (u32)__builtin_nontemporal_load(&rank[e]);
        } else {
            pos = atomicAdd(&cursor[r], 1u);
        }
        u32 c  = (u32)__builtin_nontemporal_load(&ei[NEDGES + e]);
        u32 wb = (u32)f2b(__builtin_nontemporal_load(&ew[e])) & 0x7fffu;
        erec[pos] = (c << 15) | wb;                // plain store: let L2 merge lines
        return;
    }
    // gemm role: 4 waves, 16 nodes each, MFMA over the 3 Gram matrices
    __shared__ u16 xs[4][16][DD];
    int w = t >> 6, l = t & 63;
    int l15 = l & 15, lq = l >> 4;
    int nb = (b/9)*64 + w*16;
    if (nb >= NNODES) return;

    const v8s* xbv = (const v8s*)(xb + (size_t)(nb + l15)*DD);
    v8s af[4];
    #pragma unroll
    for (int kk = 0; kk < 4; ++kk) {
        af[kk] = xbv[kk*4 + lq];
        *(v8s*)&xs[w][l15][kk*32 + lq*8] = af[kk];
    }
    const v8s* gf = (const v8s*)ws;                // OFF_GFRAG = 0
    float* phichi = ws + OFF_PHICHI/4;
    float* vsx    = ws + OFF_VSX/4;
    float sa4[4] = {0.f, 0.f, 0.f, 0.f};

    #pragma unroll
    for (int mat = 0; mat < 3; ++mat) {
        v4f acc[8];
        #pragma unroll
        for (int nt = 0; nt < 8; ++nt) acc[nt] = (v4f){0.f,0.f,0.f,0.f};
        #pragma unroll
        for (int kk = 0; kk < 4; ++kk)
            #pragma unroll
            for (int nt = 0; nt < 8; ++nt)
                acc[nt] = __builtin_amdgcn_mfma_f32_16x16x32_bf16(
                    af[kk], gf[((mat*8 + nt)*4 + kk)*64 + l], acc[nt], 0, 0, 0);
        // D[m][n]: m = lq*4 + r (node), n = nt*16 + l15 (dim)
        if (mat < 2) {                             // quantize a/b to i8, per-node scale
            float mx[4] = {0.f, 0.f, 0.f, 0.f};
            #pragma unroll
            for (int nt = 0; nt < 8; ++nt)
                #pragma unroll
                for (int r = 0; r < 4; ++r)
                    mx[r] = fmaxf(mx[r], fabsf(acc[nt][r]));
            #pragma unroll
            for (int mask = 1; mask < 16; mask <<= 1)
                #pragma unroll
                for (int r = 0; r < 4; ++r)
                    mx[r] = fmaxf(mx[r], __shfl_xor(mx[r], mask));
            float iv[4], sc[4];
            #pragma unroll
            for (int r = 0; r < 4; ++r) {
                iv[r] = (mx[r] > 0.f) ? 127.f/mx[r] : 0.f;
                sc[r] = mx[r] * (1.f/127.f);
            }
            char* qdst = mat ? bq : aq;
            #pragma unroll
            for (int nt = 0; nt < 8; ++nt)
                #pragma unroll
                for (int r = 0; r < 4; ++r)
                    qdst[(size_t)(nb + lq*4 + r)*128 + nt*16 + l15] =
                        (char)(int)rintf(acc[nt][r]*iv[r]);
            if (mat == 0) {
                #pragma unroll
                for (int r = 0; r < 4; ++r) sa4[r] = sc[r];
            } else if (l15 == 0) {
                #pragma unroll
                for (int r = 0; r < 4; ++r)
                    *(v2f*)&absc[2*(nb + lq*4 + r)] = (v2f){sa4[r], sc[r]};
            }
        }
        if (mat >= 1) {                            // x . (G x): vsq (mat1), phichi (mat2)
            float p0 = 0.f, p1 = 0.f, p2 = 0.f, p3 = 0.f;
            #pragma unroll
            for (int nt = 0; nt < 8; ++nt) {
                int nn = nt*16 + l15;
                p0 = fmaf(b2f16(xs[w][lq*4+0][nn]), acc[nt][0], p0);
                p1 = fmaf(b2f16(xs[w][lq*4+1][nn]), acc[nt][1], p1);
                p2 = fmaf(b2f16(xs[w][lq*4+2][nn]), acc[nt][2], p2);
                p3 = fmaf(b2f16(xs[w][lq*4+3][nn]), acc[nt][3], p3);
            }
            #pragma unroll
            for (int mask = 1; mask < 16; mask <<= 1) {
                p0 += __shfl_xor(p0, mask);
                p1 += __shfl_xor(p1, mask);
                p2 += __shfl_xor(p2, mask);
                p3 += __shfl_xor(p3, mask);
            }
            if (l15 == 0) {
                int n0 = nb + lq*4;
                if (mat == 1) {
                    vsx[2*(n0+0)] = p0; vsx[2*(n0+1)] = p1;
                    vsx[2*(n0+2)] = p2; vsx[2*(n0+3)] = p3;
                } else {
                    phichi[n0+0] = tanh_pos(sqrtf(fmaxf(p0, 0.f)));
                    phichi[n0+1] = tanh_pos(sqrtf(fmaxf(p1, 0.f)));
                    phichi[n0+2] = tanh_pos(sqrtf(fmaxf(p2, 0.f)));
                    phichi[n0+3] = tanh_pos(sqrtf(fmaxf(p3, 0.f)));
                }
            }
        }
    }
}

// one wave per node; 16 edges per i8-MFMA tile (K=128 via 2 chained MFMAs).
// R9's proven form (1-deep prefetch, minimal state) — byte-identical to R12.
__global__ __launch_bounds__(256) void k_accum(const float* __restrict__ x,
                                               const float* __restrict__ phichi,
                                               const float* __restrict__ vsx,
                                               const float* __restrict__ absc,
                                               const u32* __restrict__ start,
                                               const u32* __restrict__ erec,
                                               const char* __restrict__ xq,
                                               const char* __restrict__ aq,
                                               const char* __restrict__ bq,
                                               float* __restrict__ out) {
    __shared__ float red[4][8][132];
    int w = threadIdx.x >> 6, lane = threadIdx.x & 63;
    int node = blockIdx.x*4 + w;
    int l15 = lane & 15, lq = lane >> 4;

    u32 s0 = start[node];
    u32 n  = start[node+1] - s0;
    float vq_r = vsx[2*node];
    float2 sab = *(const float2*)&absc[2*node];

    v4i zero4 = {0, 0, 0, 0};
    v4i afr[2];
    {
        const char* src = (l15 == 1) ? bq : aq;
        const v4i* p = (const v4i*)(src + (size_t)node*128);
        bool keep = (l15 < 2);
        #pragma unroll
        for (int kk = 0; kk < 2; ++kk) {
            v4i v = p[kk*4 + lq];
            afr[kk] = keep ? v : zero4;
        }
    }

    float accl[2][16];
    #pragma unroll
    for (int kk = 0; kk < 2; ++kk)
        #pragma unroll
        for (int j = 0; j < 16; ++j) accl[kk][j] = 0.f;
    float sphi = 0.f, wsum = 0.f;

    u32 ntiles = (n + 15) >> 4;

    auto ldr = [&](u32 tt) -> u32 {
        u32 off = tt*16 + (u32)l15;
        u32 eidx = (off < n) ? (s0 + off) : s0;
        return __builtin_nontemporal_load(&erec[eidx]);
    };

    if (ntiles) {
        u32 rc = ldr(0);
        for (u32 tt = 0; tt < ntiles; ++tt) {
            u32 rn = (tt + 1 < ntiles) ? ldr(tt + 1) : rc;
            u32 c = rc >> 15;
            bool valid = (tt*16 + (u32)l15) < n;
            float w_e = valid ? __uint_as_float((rc & 0x7fffu) << 16) : 0.f;
            float2 vx = *(const float2*)&vsx[2*c];   // (vsq_c, sx_c)
            const v4i* xcv = (const v4i*)(xq + (size_t)c*128);
            v4i bfr[2];
            bfr[0] = xcv[lq];
            bfr[1] = xcv[4 + lq];

            v4i d = zero4;
            d = __builtin_amdgcn_mfma_i32_16x16x64_i8(afr[0], bfr[0], d, 0, 0, 0);
            d = __builtin_amdgcn_mfma_i32_16x16x64_i8(afr[1], bfr[1], d, 0, 0, 0);
            // lq==0 lanes: d[0]=adot_int(edge l15), d[1]=bdot_int; others exact 0
            float adot = (float)d[0] * (sab.x * vx.y);
            float bdot = (float)d[1] * (sab.y * vx.y);
            float ss = fmaxf(vq_r + vx.x - 2.f*bdot, 0.f);
            float psi = w_e * tanh_pos(fabsf(adot)) * tanh_pos(__fdividef(1.f, sqrtf(ss) + EPSF));
            float psi_b = __shfl(psi, l15);          // edge l15's psi to all lq groups
            sphi += psi_b;
            wsum += w_e;
            float psx = psi_b * vx.y;                // fold sx_c into the accumulate
            #pragma unroll
            for (int kk = 0; kk < 2; ++kk) {
                const int* pw = (const int*)&bfr[kk];
                #pragma unroll
                for (int wd = 0; wd < 4; ++wd) {
                    int word = pw[wd];
                    accl[kk][wd*4+0] = fmaf(psx, (float)((word << 24) >> 24), accl[kk][wd*4+0]);
                    accl[kk][wd*4+1] = fmaf(psx, (float)((word << 16) >> 24), accl[kk][wd*4+1]);
                    accl[kk][wd*4+2] = fmaf(psx, (float)((word <<  8) >> 24), accl[kk][wd*4+2]);
                    accl[kk][wd*4+3] = fmaf(psx, (float)( word        >> 24), accl[kk][wd*4+3]);
                }
            }
            rc = rn;
        }
    }

    // reduce sphi/wsum over the 16 edge-slots
    #pragma unroll
    for (int mask = 1; mask < 16; mask <<= 1) {
        sphi += __shfl_xor(sphi, mask);
        wsum += __shfl_xor(wsum, mask);
    }

    // pre-reduce accl over adjacent edge-slot pairs, then LDS transpose-reduce
    #pragma unroll
    for (int kk = 0; kk < 2; ++kk)
        #pragma unroll
        for (int j = 0; j < 16; ++j)
            accl[kk][j] += __shfl_xor(accl[kk][j], 1);

    if ((l15 & 1) == 0) {
        int e8 = l15 >> 1;
        #pragma unroll
        for (int kk = 0; kk < 2; ++kk) {
            int base = kk*64 + lq*16;                // dim = kk*64 + lq*16 + j
            *(float4*)&red[w][e8][base]      = *(float4*)&accl[kk][0];
            *(float4*)&red[w][e8][base + 4]  = *(float4*)&accl[kk][4];
            *(float4*)&red[w][e8][base + 8]  = *(float4*)&accl[kk][8];
            *(float4*)&red[w][e8][base + 12] = *(float4*)&accl[kk][12];
        }
    }
    __syncthreads();
    float a0 = 0.f, a1 = 0.f;
    #pragma unroll
    for (int e = 0; e < 8; ++e) {
        float2 v = *(const float2*)&red[w][e][lane*2];
        a0 += v.x; a1 += v.y;
    }

    float ia = (n == 0) ? 0.f : __fdividef(1.f, wsum * phichi[node]);
    float scale = 1.f - ia * sphi;
    float2 xv = *(const float2*)(x + (size_t)node*DD + lane*2);
    v2f o;
    o.x = xv.x*scale + ia*a0;
    o.y = xv.y*scale + ia*a1;
    __builtin_nontemporal_store(o, (v2f*)(out + (size_t)node*DD + lane*2));
}

extern "C" void kernel_launch(void* const* d_in, const int* in_sizes, int n_in,
                              void* d_out, int out_size, void* d_ws, size_t ws_size,
                              hipStream_t stream) {
    const float* x     = (const float*)d_in[0];
    const int*   ei    = (const int*)d_in[1];
    const float* ew    = (const float*)d_in[2];
    const float* Wchi  = (const float*)d_in[3];
    const float* Wphi  = (const float*)d_in[4];
    const float* Wvphi = (const float*)d_in[5];
    float* out = (float*)d_out;
    float* ws  = (float*)d_ws;
    char*  wsb = (char*)d_ws;

    float* phichi = (float*)(wsb + OFF_PHICHI);
    float* vsx    = (float*)(wsb + OFF_VSX);
    u32*   cnt    = (u32*)  (wsb + OFF_CNT);
    u32*   cursor = (u32*)  (wsb + OFF_CNT);    // alias: cnt dead after scans
    u32*   start  = (u32*)  (wsb + OFF_START);
    u32*   bsum   = (u32*)  (wsb + OFF_BSUM);
    u16*   gf     = (u16*)  (wsb + OFF_GFRAG);
    float* absc   = (float*)(wsb + OFF_ABSC);
    char*  aq     = (char*) (wsb + OFF_AQ);
    char*  bq     = (char*) (wsb + OFF_BQ);
    u16*   xb     = (u16*)  (wsb + OFF_XB);
    char*  xq     = (char*) (wsb + OFF_XQ);
    u32*   erec   = (u32*)  (wsb + OFF_EREC);
    float* wcomb  = (float*)(wsb + OFF_WCOMB);  // temp, overlays erec
    u16*   rank   = (u16*)  (wsb + OFF_RANK);
    u16*   cbase  = (u16*)  (wsb + OFF_CBASE);

    bool use_rank = (ws_size >= (size_t)WS_NEED_RANK);

    if (use_rank) {
        k_hist<<<dim3(NPART*NRG), dim3(256), 0, stream>>>(ei, rank, cbase);
        k_prep<true><<<dim3(XBLK+192), dim3(256), 0, stream>>>(ei, x, Wchi, Wphi, Wvphi,
                                                               cnt, xb, xq, vsx, wcomb, gf);
        k_rowsum_bsum<true><<<dim3(NB_SCAN+64), dim3(256), 0, stream>>>(cbase, cnt, bsum,
                                                                        wcomb, gf);
    } else {
        hipError_t err = hipMemsetAsync(wsb + OFF_CNT, 0, 200000, stream);
        (void)err;
        k_prep<false><<<dim3(HB+XBLK+192), dim3(256), 0, stream>>>(ei, x, Wchi, Wphi, Wvphi,
                                                                   cnt, xb, xq, vsx, wcomb, gf);
        k_rowsum_bsum<false><<<dim3(NB_SCAN+64), dim3(256), 0, stream>>>(cbase, cnt, bsum,
                                                                         wcomb, gf);
    }
    k_scan_final<<<dim3(NB_SCAN), dim3(256), 0, stream>>>(cnt, bsum, start, cursor);
    if (use_rank) {
        k_mid<true><<<dim3(SB+GB), dim3(256), 0, stream>>>(ei, ew, start, cursor, rank, cbase,
                                                           erec, xb, ws, aq, bq, absc);
    } else {
        k_mid<false><<<dim3(SB+GB), dim3(256), 0, stream>>>(ei, ew, start, cursor, rank, cbase,
                                                            erec, xb, ws, aq, bq, absc);
    }
    k_accum<<<dim3(NNODES/4), dim3(256), 0, stream>>>(x, phichi, vsx, absc, start, erec,
                                                      xq, aq, bq, out);
}

// Round 15
// 198.213 us; speedup vs baseline: 1.2576x; 1.2576x over previous
//
#include <hip/hip_runtime.h>
#include <hip/hip_bf16.h>

#define NNODES 50000
#define NEDGES 1600000
#define DD 128
#define EPSF 1e-6f
#define NB_SCAN 196   // ceil(50000/256)
#define NPART 128     // edge partitions (R15: 512 hist blocks, 49 iters each)
#define EPP 12500     // edges per partition (NPART*EPP = NEDGES)
#define NRG 4         // rowgroups
#define RGSZ 12500    // rows per rowgroup (NRG*RGSZ = NNODES), 50KB LDS

using u32 = unsigned int;
using u16 = unsigned short;
using u64 = unsigned long long;
typedef __attribute__((ext_vector_type(8))) short v8s;   // 8 x bf16 (4 VGPR)
typedef __attribute__((ext_vector_type(4))) float v4f;   // mfma accumulator
typedef __attribute__((ext_vector_type(4))) int   v4i;   // i8 mfma operand (16 i8)
typedef __attribute__((ext_vector_type(2))) float v2f;   // nontemporal-storable pair

static __device__ __forceinline__ float b2f16(u16 v) { return __uint_as_float(((u32)v) << 16); }
static __device__ __forceinline__ u16 f2b(float f) {
    u32 u = __float_as_uint(f);
    return (u16)((u + 0x7fffu + ((u >> 16) & 1u)) >> 16);
}
static __device__ __forceinline__ float tanh_pos(float a) {   // a >= 0, fast
    float e = __expf(-2.f * a);
    return __fdividef(1.f - e, 1.f + e);
}

// workspace byte offsets — ALL gather pools 128B-aligned
#define OFF_GFRAG  0          // 3 * 32KB bf16 Gram matrices in MFMA B-frag layout
#define OFF_PHICHI 98304      // 50000 f32
#define OFF_VSX    298304     // 50000 float2 : (vsq, xscale) per node
#define OFF_CNT    698304     // 50000 u32 row totals (cursor alias in fallback)
#define OFF_START  898304     // 50001 u32 (pad to 200064)
#define OFF_BSUM   1098368    // 196 u32 (pad 1024)
#define OFF_ABSC   1100416    // 50000 float2 : (ascale, bscale)
#define OFF_AQ     1500416    // 50000*128 i8 (128-aligned)
#define OFF_BQ     7900416    // 50000*128 i8 (128-aligned)
#define OFF_XB     14300416   // 50000*128 bf16 (128-aligned)
#define OFF_XQ     27100416   // 50000*128 i8 gather pool (128-aligned)
#define OFF_EREC   33500416   // 1.6M u32 : (col<<15)|bf16w (64-aligned)
#define OFF_WCOMB  33500416   // 128*128 f32 TEMP, overlays EREC (dead before k_mid)
#define OFF_RANK   39900416   // 1.6M u16 : rank within (partition,row)
#define OFF_CBASE  43100416   // 128*50000 u16 : per-(part,row) counts -> excl bases (12.8MB)
#define WS_NEED_RANK 55900416ull

// store val=G[a][c] into MFMA B-fragment layout for mfma_f32_16x16x32_bf16
static __device__ __forceinline__ void gstore(u16* gf, int mat, int a, int c, float v) {
    int lane = (((a >> 3) & 3) << 4) | (c & 15);
    int u = ((((mat*8 + (c >> 4))*4 + (a >> 5))*64 + lane) << 3) | (a & 7);
    gf[u] = f2b(v);
}

#define HB (NEDGES/256)       // 6250 fallback hist blocks
#define XBLK (NNODES/4)       // 12500 x-quant blocks (1 node/wave)

// SEPARATE k_hist: 128 partitions x 4 rowgroups = 512 blocks (2/CU), 49
// serial iterations each (R14 lesson: time ∝ EPP at block-starved grids).
__global__ __launch_bounds__(256) void k_hist(const int* __restrict__ ei,
                                              u16* __restrict__ rank,
                                              u16* __restrict__ cbase) {
    __shared__ u32 lcnt[RGSZ];
    int p = blockIdx.x >> 2, rg = blockIdx.x & 3;
    int t = threadIdx.x;
    for (int i = t; i < RGSZ; i += 256) lcnt[i] = 0;
    __syncthreads();
    int base = rg * RGSZ;
    for (int i = t; i < EPP; i += 256) {
        int e = p*EPP + i;
        int r = ei[e];
        u32 rr = (u32)(r - base);
        if (rr < RGSZ) {
            u32 old = atomicAdd(&lcnt[rr], 1u);   // LDS atomic, returns order
            rank[e] = (u16)old;
        }
    }
    __syncthreads();
    u16* dst = cbase + (size_t)p*NNODES + base;
    for (int i = t; i < RGSZ; i += 256) dst[i] = (u16)lcnt[i];
}

// RANK path: quant (XBLK blocks) + weight GEMMs (192 blocks). No LDS.
// Fallback: + HB device-atomic histogram blocks in front.
template<bool RANK>
__global__ __launch_bounds__(256) void k_prep(const int* __restrict__ ei,
                                              const float* __restrict__ x,
                                              const float* __restrict__ Wchi,
                                              const float* __restrict__ Wphi,
                                              const float* __restrict__ Wvphi,
                                              u32* __restrict__ cnt,
                                              u16* __restrict__ xb,
                                              char* __restrict__ xq,
                                              float* __restrict__ vsx,
                                              float* __restrict__ wcomb,
                                              u16* __restrict__ gf) {
    int b = blockIdx.x, t = threadIdx.x;
    if (!RANK) {
        if (b < HB) {                              // fallback: device-atomic histogram
            atomicAdd(&cnt[ei[b*256 + t]], 1u);
            return;
        }
        b -= HB;
    }
    if (b < XBLK) {
        // x -> bf16 xb + i8 xq (per-node absmax scale). 1 node per wave.
        int w = t >> 6, lane = t & 63;
        int node = b*4 + w;
        float2 xv = ((const float2*)(x + (size_t)node*DD))[lane];
        u32 pk = (u32)f2b(xv.x) | ((u32)f2b(xv.y) << 16);
        ((u32*)xb)[node*64 + lane] = pk;
        float m = fmaxf(fabsf(xv.x), fabsf(xv.y));
        #pragma unroll
        for (int mask = 1; mask < 64; mask <<= 1)
            m = fmaxf(m, __shfl_xor(m, mask));
        float inv = (m > 0.f) ? 127.f/m : 0.f;
        int q0 = (int)rintf(xv.x*inv), q1 = (int)rintf(xv.y*inv);
        ((u16*)xq)[node*64 + lane] = (u16)((q0 & 0xff) | ((q1 & 0xff) << 8));
        if (lane == 0) vsx[2*node + 1] = m * (1.f/127.f);
        return;
    }
    // weight role: bb<64 -> Wcomb = Wphi@Wchi (fp32 temp);
    //              bb<128 -> Bgram -> frag mat 1;  else Cgram -> frag mat 2
    int bb = b - XBLK;
    if (bb < 64) {
        int idx = bb*256 + t;
        int i = idx >> 7, k = idx & 127;
        float acc = 0.f;
        #pragma unroll 8
        for (int m = 0; m < DD; ++m)
            acc = fmaf(Wphi[i*DD+m], Wchi[m*DD+k], acc);
        wcomb[i*DD+k] = acc;
    } else {
        const float* W = (bb < 128) ? Wvphi : Wchi;
        int mat = (bb < 128) ? 1 : 2;
        int idx = ((bb & 63))*256 + t;
        int a = idx >> 7, c = idx & 127;
        float acc = 0.f;
        #pragma unroll 8
        for (int m = 0; m < DD; ++m)
            acc = fmaf(W[m*DD+a], W[m*DD+c], acc);
        gstore(gf, mat, a, c, acc);
    }
}

// FUSED: rowsum (cbase counts -> exclusive prefixes + cnt) + per-block degree
// sums, block-local dependency only. Blocks >= NB_SCAN compute Agram -> frag mat 0.
template<bool RANK>
__global__ __launch_bounds__(256) void k_rowsum_bsum(u16* __restrict__ cbase,
                                                     u32* __restrict__ cnt,
                                                     u32* __restrict__ bsum,
                                                     const float* __restrict__ wcomb,
                                                     u16* __restrict__ gf) {
    if (blockIdx.x >= NB_SCAN) {
        int idx = (blockIdx.x - NB_SCAN)*256 + threadIdx.x;
        int a = idx >> 7, c = idx & 127;
        float acc = 0.f;
        #pragma unroll 8
        for (int m = 0; m < DD; ++m)
            acc = fmaf(wcomb[m*DD+a], wcomb[m*DD+c], acc);
        gstore(gf, 0, a, c, acc);
        return;
    }
    __shared__ u32 s[256];
    int r = blockIdx.x*256 + threadIdx.x;
    u32 running = 0;
    if (RANK) {
        if (r < NNODES) {
            #pragma unroll 8
            for (int p = 0; p < NPART; ++p) {
                u32 c = cbase[(size_t)p*NNODES + r];
                cbase[(size_t)p*NNODES + r] = (u16)running;
                running += c;
            }
            cnt[r] = running;
        }
    } else {
        running = (r < NNODES) ? cnt[r] : 0u;
    }
    s[threadIdx.x] = (r < NNODES) ? running : 0u;
    __syncthreads();
    for (int off = 128; off > 0; off >>= 1) {
        if (threadIdx.x < off) s[threadIdx.x] += s[threadIdx.x + off];
        __syncthreads();
    }
    if (threadIdx.x == 0) bsum[blockIdx.x] = s[0];
}

// FUSED: block-exclusive boff computed inline (sum of bsum[0..bid)), then
// the per-block scan of cnt. One fewer launch.
__global__ __launch_bounds__(256) void k_scan_final(const u32* __restrict__ cnt,
                                                    const u32* __restrict__ bsum,
                                                    u32* __restrict__ start,
                                                    u32* __restrict__ cursor) {
    __shared__ u32 s[256];
    __shared__ u32 sb[256];
    int t = threadIdx.x;
    u32 pre = 0;
    for (int j = t; j < (int)blockIdx.x; j += 256) pre += bsum[j];
    sb[t] = pre;
    __syncthreads();
    for (int off = 128; off > 0; off >>= 1) {
        if (t < off) sb[t] += sb[t + off];
        __syncthreads();
    }
    u32 boff = sb[0];
    int i = blockIdx.x*256 + t;
    u32 v = (i < NNODES) ? cnt[i] : 0u;
    s[t] = v;
    __syncthreads();
    for (int off = 1; off < 256; off <<= 1) {
        u32 a = (t >= off) ? s[t - off] : 0u;
        __syncthreads();
        s[t] += a;
        __syncthreads();
    }
    if (i < NNODES) {
        u32 val = boff + (s[t] - v);
        start[i]  = val;
        cursor[i] = val;
        if (i == NNODES-1) start[NNODES] = val + v;
    }
}

#define SB (NEDGES/256)       // 6250 scatter blocks
#define GB 782                // gemm blocks: 64 nodes each
// grid = SB + GB = 7032; b%9==0 -> gemm (782 exactly), else scatter

template<bool RANK>
__global__ __launch_bounds__(256) void k_mid(const int* __restrict__ ei,
                                             const float* __restrict__ ew,
                                             const u32* __restrict__ start,
                                             u32* __restrict__ cursor,
                                             const u16* __restrict__ rank,
                                             const u16* __restrict__ cbase,
                                             u32* __restrict__ erec,
                                             const u16* __restrict__ xb,
                                             float* __restrict__ ws,
                                             char* __restrict__ aq,
                                             char* __restrict__ bq,
                                             float* __restrict__ absc) {
    int b = blockIdx.x, t = threadIdx.x;
    if (b % 9 != 0) {                              // scatter into CSR (4B packed record)
        int eb = b - b/9 - 1;
        int e = eb*256 + t;
        int r = __builtin_nontemporal_load(&ei[e]);
        u32 pos;
        if (RANK) {
            int p = e / EPP;                       // partition, same map as k_hist
            pos = start[r] + (u32)cbase[(size_t)p*NNODES + r]
                + (u32)__builtin_nontemporal_load(&rank[e]);
        } else {
            pos = atomicAdd(&cursor[r], 1u);
        }
        u32 c  = (u32)__builtin_nontemporal_load(&ei[NEDGES + e]);
        u32 wb = (u32)f2b(__builtin_nontemporal_load(&ew[e])) & 0x7fffu;
        erec[pos] = (c << 15) | wb;                // plain store: let L2 merge lines
        return;
    }
    // gemm role: 4 waves, 16 nodes each, MFMA over the 3 Gram matrices
    __shared__ u16 xs[4][16][DD];
    int w = t >> 6, l = t & 63;
    int l15 = l & 15, lq = l >> 4;
    int nb = (b/9)*64 + w*16;
    if (nb >= NNODES) return;

    const v8s* xbv = (const v8s*)(xb + (size_t)(nb + l15)*DD);
    v8s af[4];
    #pragma unroll
    for (int kk = 0; kk < 4; ++kk) {
        af[kk] = xbv[kk*4 + lq];
        *(v8s*)&xs[w][l15][kk*32 + lq*8] = af[kk];
    }
    const v8s* gf = (const v8s*)ws;                // OFF_GFRAG = 0
    float* phichi = ws + OFF_PHICHI/4;
    float* vsx    = ws + OFF_VSX/4;
    float sa4[4] = {0.f, 0.f, 0.f, 0.f};

    #pragma unroll
    for (int mat = 0; mat < 3; ++mat) {
        v4f acc[8];
        #pragma unroll
        for (int nt = 0; nt < 8; ++nt) acc[nt] = (v4f){0.f,0.f,0.f,0.f};
        #pragma unroll
        for (int kk = 0; kk < 4; ++kk)
            #pragma unroll
            for (int nt = 0; nt < 8; ++nt)
                acc[nt] = __builtin_amdgcn_mfma_f32_16x16x32_bf16(
                    af[kk], gf[((mat*8 + nt)*4 + kk)*64 + l], acc[nt], 0, 0, 0);
        // D[m][n]: m = lq*4 + r (node), n = nt*16 + l15 (dim)
        if (mat < 2) {                             // quantize a/b to i8, per-node scale
            float mx[4] = {0.f, 0.f, 0.f, 0.f};
            #pragma unroll
            for (int nt = 0; nt < 8; ++nt)
                #pragma unroll
                for (int r = 0; r < 4; ++r)
                    mx[r] = fmaxf(mx[r], fabsf(acc[nt][r]));
            #pragma unroll
            for (int mask = 1; mask < 16; mask <<= 1)
                #pragma unroll
                for (int r = 0; r < 4; ++r)
                    mx[r] = fmaxf(mx[r], __shfl_xor(mx[r], mask));
            float iv[4], sc[4];
            #pragma unroll
            for (int r = 0; r < 4; ++r) {
                iv[r] = (mx[r] > 0.f) ? 127.f/mx[r] : 0.f;
                sc[r] = mx[r] * (1.f/127.f);
            }
            char* qdst = mat ? bq : aq;
            #pragma unroll
            for (int nt = 0; nt < 8; ++nt)
                #pragma unroll
                for (int r = 0; r < 4; ++r)
                    qdst[(size_t)(nb + lq*4 + r)*128 + nt*16 + l15] =
                        (char)(int)rintf(acc[nt][r]*iv[r]);
            if (mat == 0) {
                #pragma unroll
                for (int r = 0; r < 4; ++r) sa4[r] = sc[r];
            } else if (l15 == 0) {
                #pragma unroll
                for (int r = 0; r < 4; ++r)
                    *(v2f*)&absc[2*(nb + lq*4 + r)] = (v2f){sa4[r], sc[r]};
            }
        }
        if (mat >= 1) {                            // x . (G x): vsq (mat1), phichi (mat2)
            float p0 = 0.f, p1 = 0.f, p2 = 0.f, p3 = 0.f;
            #pragma unroll
            for (int nt = 0; nt < 8; ++nt) {
                int nn = nt*16 + l15;
                p0 = fmaf(b2f16(xs[w][lq*4+0][nn]), acc[nt][0], p0);
                p1 = fmaf(b2f16(xs[w][lq*4+1][nn]), acc[nt][1], p1);
                p2 = fmaf(b2f16(xs[w][lq*4+2][nn]), acc[nt][2], p2);
                p3 = fmaf(b2f16(xs[w][lq*4+3][nn]), acc[nt][3], p3);
            }
            #pragma unroll
            for (int mask = 1; mask < 16; mask <<= 1) {
                p0 += __shfl_xor(p0, mask);
                p1 += __shfl_xor(p1, mask);
                p2 += __shfl_xor(p2, mask);
                p3 += __shfl_xor(p3, mask);
            }
            if (l15 == 0) {
                int n0 = nb + lq*4;
                if (mat == 1) {
                    vsx[2*(n0+0)] = p0; vsx[2*(n0+1)] = p1;
                    vsx[2*(n0+2)] = p2; vsx[2*(n0+3)] = p3;
                } else {
                    phichi[n0+0] = tanh_pos(sqrtf(fmaxf(p0, 0.f)));
                    phichi[n0+1] = tanh_pos(sqrtf(fmaxf(p1, 0.f)));
                    phichi[n0+2] = tanh_pos(sqrtf(fmaxf(p2, 0.f)));
                    phichi[n0+3] = tanh_pos(sqrtf(fmaxf(p3, 0.f)));
                }
            }
        }
    }
}

// one wave per node; 16 edges per i8-MFMA tile (K=128 via 2 chained MFMAs).
// R9's proven form (1-deep prefetch, minimal state) — byte-identical to R12.
__global__ __launch_bounds__(256) void k_accum(const float* __restrict__ x,
                                               const float* __restrict__ phichi,
                                               const float* __restrict__ vsx,
                                               const float* __restrict__ absc,
                                               const u32* __restrict__ start,
                                               const u32* __restrict__ erec,
                                               const char* __restrict__ xq,
                                               const char* __restrict__ aq,
                                               const char* __restrict__ bq,
                                               float* __restrict__ out) {
    __shared__ float red[4][8][132];
    int w = threadIdx.x >> 6, lane = threadIdx.x & 63;
    int node = blockIdx.x*4 + w;
    int l15 = lane & 15, lq = lane >> 4;

    u32 s0 = start[node];
    u32 n  = start[node+1] - s0;
    float vq_r = vsx[2*node];
    float2 sab = *(const float2*)&absc[2*node];

    v4i zero4 = {0, 0, 0, 0};
    v4i afr[2];
    {
        const char* src = (l15 == 1) ? bq : aq;
        const v4i* p = (const v4i*)(src + (size_t)node*128);
        bool keep = (l15 < 2);
        #pragma unroll
        for (int kk = 0; kk < 2; ++kk) {
            v4i v = p[kk*4 + lq];
            afr[kk] = keep ? v : zero4;
        }
    }

    float accl[2][16];
    #pragma unroll
    for (int kk = 0; kk < 2; ++kk)
        #pragma unroll
        for (int j = 0; j < 16; ++j) accl[kk][j] = 0.f;
    float sphi = 0.f, wsum = 0.f;

    u32 ntiles = (n + 15) >> 4;

    auto ldr = [&](u32 tt) -> u32 {
        u32 off = tt*16 + (u32)l15;
        u32 eidx = (off < n) ? (s0 + off) : s0;
        return __builtin_nontemporal_load(&erec[eidx]);
    };

    if (ntiles) {
        u32 rc = ldr(0);
        for (u32 tt = 0; tt < ntiles; ++tt) {
            u32 rn = (tt + 1 < ntiles) ? ldr(tt + 1) : rc;
            u32 c = rc >> 15;
            bool valid = (tt*16 + (u32)l15) < n;
            float w_e = valid ? __uint_as_float((rc & 0x7fffu) << 16) : 0.f;
            float2 vx = *(const float2*)&vsx[2*c];   // (vsq_c, sx_c)
            const v4i* xcv = (const v4i*)(xq + (size_t)c*128);
            v4i bfr[2];
            bfr[0] = xcv[lq];
            bfr[1] = xcv[4 + lq];

            v4i d = zero4;
            d = __builtin_amdgcn_mfma_i32_16x16x64_i8(afr[0], bfr[0], d, 0, 0, 0);
            d = __builtin_amdgcn_mfma_i32_16x16x64_i8(afr[1], bfr[1], d, 0, 0, 0);
            // lq==0 lanes: d[0]=adot_int(edge l15), d[1]=bdot_int; others exact 0
            float adot = (float)d[0] * (sab.x * vx.y);
            float bdot = (float)d[1] * (sab.y * vx.y);
            float ss = fmaxf(vq_r + vx.x - 2.f*bdot, 0.f);
            float psi = w_e * tanh_pos(fabsf(adot)) * tanh_pos(__fdividef(1.f, sqrtf(ss) + EPSF));
            float psi_b = __shfl(psi, l15);          // edge l15's psi to all lq groups
            sphi += psi_b;
            wsum += w_e;
            float psx = psi_b * vx.y;                // fold sx_c into the accumulate
            #pragma unroll
            for (int kk = 0; kk < 2; ++kk) {
                const int* pw = (const int*)&bfr[kk];
                #pragma unroll
                for (int wd = 0; wd < 4; ++wd) {
                    int word = pw[wd];
                    accl[kk][wd*4+0] = fmaf(psx, (float)((word << 24) >> 24), accl[kk][wd*4+0]);
                    accl[kk][wd*4+1] = fmaf(psx, (float)((word << 16) >> 24), accl[kk][wd*4+1]);
                    accl[kk][wd*4+2] = fmaf(psx, (float)((word <<  8) >> 24), accl[kk][wd*4+2]);
                    accl[kk][wd*4+3] = fmaf(psx, (float)( word        >> 24), accl[kk][wd*4+3]);
                }
            }
            rc = rn;
        }
    }

    // reduce sphi/wsum over the 16 edge-slots
    #pragma unroll
    for (int mask = 1; mask < 16; mask <<= 1) {
        sphi += __shfl_xor(sphi, mask);
        wsum += __shfl_xor(wsum, mask);
    }

    // pre-reduce accl over adjacent edge-slot pairs, then LDS transpose-reduce
    #pragma unroll
    for (int kk = 0; kk < 2; ++kk)
        #pragma unroll
        for (int j = 0; j < 16; ++j)
            accl[kk][j] += __shfl_xor(accl[kk][j], 1);

    if ((l15 & 1) == 0) {
        int e8 = l15 >> 1;
        #pragma unroll
        for (int kk = 0; kk < 2; ++kk) {
            int base = kk*64 + lq*16;                // dim = kk*64 + lq*16 + j
            *(float4*)&red[w][e8][base]      = *(float4*)&accl[kk][0];
            *(float4*)&red[w][e8][base + 4]  = *(float4*)&accl[kk][4];
            *(float4*)&red[w][e8][base + 8]  = *(float4*)&accl[kk][8];
            *(float4*)&red[w][e8][base + 12] = *(float4*)&accl[kk][12];
        }
    }
    __syncthreads();
    float a0 = 0.f, a1 = 0.f;
    #pragma unroll
    for (int e = 0; e < 8; ++e) {
        float2 v = *(const float2*)&red[w][e][lane*2];
        a0 += v.x; a1 += v.y;
    }

    float ia = (n == 0) ? 0.f : __fdividef(1.f, wsum * phichi[node]);
    float scale = 1.f - ia * sphi;
    float2 xv = *(const float2*)(x + (size_t)node*DD + lane*2);
    v2f o;
    o.x = xv.x*scale + ia*a0;
    o.y = xv.y*scale + ia*a1;
    __builtin_nontemporal_store(o, (v2f*)(out + (size_t)node*DD + lane*2));
}

extern "C" void kernel_launch(void* const* d_in, const int* in_sizes, int n_in,
                              void* d_out, int out_size, void* d_ws, size_t ws_size,
                              hipStream_t stream) {
    const float* x     = (const float*)d_in[0];
    const int*   ei    = (const int*)d_in[1];
    const float* ew    = (const float*)d_in[2];
    const float* Wchi  = (const float*)d_in[3];
    const float* Wphi  = (const float*)d_in[4];
    const float* Wvphi = (const float*)d_in[5];
    float* out = (float*)d_out;
    float* ws  = (float*)d_ws;
    char*  wsb = (char*)d_ws;

    float* phichi = (float*)(wsb + OFF_PHICHI);
    float* vsx    = (float*)(wsb + OFF_VSX);
    u32*   cnt    = (u32*)  (wsb + OFF_CNT);
    u32*   cursor = (u32*)  (wsb + OFF_CNT);    // alias: cnt dead after scans
    u32*   start  = (u32*)  (wsb + OFF_START);
    u32*   bsum   = (u32*)  (wsb + OFF_BSUM);
    u16*   gf     = (u16*)  (wsb + OFF_GFRAG);
    float* absc   = (float*)(wsb + OFF_ABSC);
    char*  aq     = (char*) (wsb + OFF_AQ);
    char*  bq     = (char*) (wsb + OFF_BQ);
    u16*   xb     = (u16*)  (wsb + OFF_XB);
    char*  xq     = (char*) (wsb + OFF_XQ);
    u32*   erec   = (u32*)  (wsb + OFF_EREC);
    float* wcomb  = (float*)(wsb + OFF_WCOMB);  // temp, overlays erec
    u16*   rank   = (u16*)  (wsb + OFF_RANK);
    u16*   cbase  = (u16*)  (wsb + OFF_CBASE);

    bool use_rank = (ws_size >= (size_t)WS_NEED_RANK);

    if (use_rank) {
        k_hist<<<dim3(NPART*NRG), dim3(256), 0, stream>>>(ei, rank, cbase);
        k_prep<true><<<dim3(XBLK+192), dim3(256), 0, stream>>>(ei, x, Wchi, Wphi, Wvphi,
                                                               cnt, xb, xq, vsx, wcomb, gf);
        k_rowsum_bsum<true><<<dim3(NB_SCAN+64), dim3(256), 0, stream>>>(cbase, cnt, bsum,
                                                                        wcomb, gf);
    } else {
        hipError_t err = hipMemsetAsync(wsb + OFF_CNT, 0, 200000, stream);
        (void)err;
        k_prep<false><<<dim3(HB+XBLK+192), dim3(256), 0, stream>>>(ei, x, Wchi, Wphi, Wvphi,
                                                                   cnt, xb, xq, vsx, wcomb, gf);
        k_rowsum_bsum<false><<<dim3(NB_SCAN+64), dim3(256), 0, stream>>>(cbase, cnt, bsum,
                                                                         wcomb, gf);
    }
    k_scan_final<<<dim3(NB_SCAN), dim3(256), 0, stream>>>(cnt, bsum, start, cursor);
    if (use_rank) {
        k_mid<true><<<dim3(SB+GB), dim3(256), 0, stream>>>(ei, ew, start, cursor, rank, cbase,
                                                           erec, xb, ws, aq, bq, absc);
    } else {
        k_mid<false><<<dim3(SB+GB), dim3(256), 0, stream>>>(ei, ew, start, cursor, rank, cbase,
                                                            erec, xb, ws, aq, bq, absc);
    }
    k_accum<<<dim3(NNODES/4), dim3(256), 0, stream>>>(x, phichi, vsx, absc, start, erec,
                                                      xq, aq, bq, out);
}